// Round 18
// baseline (167.782 us; speedup 1.0000x reference)
//
#include <hip/hip_runtime.h>

// ResidualAttentionBlock (MFMA, round 25): B=16, FIN=256, H=W=32 (N=1024),
// NH=8, FH=64, CIN=258, COUT=512. Inputs fp32. v_mfma_f32_16x16x32_bf16,
// fp32 accumulation.
//
// Round 25 (qkv only; attn = r21 best, proj = r24 parity, prep unchanged):
//  - qkv was the purest latency-bound kernel measured (MfmaUtil 7.2% at 62us,
//    occupancy 19%); parity pipeline helped but occupancy stayed 16 waves/CU
//    (4x256thr blocks, 32.8KB LDS cap).
//  - qkv now 512-thr / 8-wave blocks, tile 256M x 128N, grid (8, 6, 16):
//    LDS 48KB (Wl 256x64 + Tl 128x64) -> 3 blocks/CU x 8 waves = 24 waves/CU
//    (+50% TLP). Per-wave acc[2][8] unchanged (VGPR ~120, 4 waves/SIMD legal).
//    xT L2 re-reads halve (6 blocks/T-panel vs 12). Same proven parity
//    pipeline: 8 steps x 1 barrier, next-step loads issued one step ahead.
//    Staging: thread = 2 W rows (srw, srw+128) + 1 T row per step.

typedef unsigned short u16;
typedef unsigned int   u32;
typedef __attribute__((ext_vector_type(8))) short  short8;
typedef __attribute__((ext_vector_type(4))) float  float4_;

#define MFMA16(a, b, c) __builtin_amdgcn_mfma_f32_16x16x32_bf16(a, b, c, 0, 0, 0)

__device__ __forceinline__ float bf2f(u16 u) {
    union { u32 i; float f; } v; v.i = ((u32)u) << 16; return v.f;
}
__device__ __forceinline__ u16 f2bf(float f) {           // RNE
    union { float f; u32 i; } v; v.f = f;
    u32 r = v.i + 0x7FFFu + ((v.i >> 16) & 1u);
    return (u16)(r >> 16);
}
__device__ __forceinline__ float exp2_fast(float x) {    // 2^x
    float r;
    asm("v_exp_f32 %0, %1" : "=v"(r) : "v"(x));
    return r;
}
__device__ __forceinline__ u32 cvtpk_bf16(float lo, float hi) {  // {bf16(lo), bf16(hi)}
    u32 r;
    asm("v_cvt_pk_bf16_f32 %0, %1, %2" : "=v"(r) : "v"(lo), "v"(hi));
    return r;
}
// rows = 16-lane groups r0..r3. p32: x'=[x0,x1,y0,y1], y'=[x2,x3,y2,y3]
__device__ __forceinline__ void pl32swap(u32 &x, u32 &y) {
    asm volatile("v_permlane32_swap_b32 %0, %1" : "+v"(x), "+v"(y));
}
// p16: x'=[x0,y0,x2,y2], y'=[x1,y1,x3,y3]
__device__ __forceinline__ void pl16swap(u32 &x, u32 &y) {
    asm volatile("v_permlane16_swap_b32 %0, %1" : "+v"(x), "+v"(y));
}

// ---------------------------------------------------------------------------
// prep: blocks [0,512) convert wq/wk/wv [512][258] fp32 -> wb [1536][256] bf16
//       blocks [512,1536) transpose x [b][256][1024] fp32 -> xT [b][1024][256]
// ---------------------------------------------------------------------------
__global__ __launch_bounds__(256) void prep(
    const float* __restrict__ wq, const float* __restrict__ wk,
    const float* __restrict__ wv, const float* __restrict__ x,
    u16* __restrict__ wb, u16* __restrict__ xT)
{
    __shared__ float Lt[64][65];
    const int bid = blockIdx.x;
    const int tid = threadIdx.x;
    if (bid < 512) {
        int i = bid * 256 + tid;
        int o = i >> 8, c = i & 255;
        size_t si = (size_t)o * 258 + c;
        wb[i]          = f2bf(wq[si]);
        wb[131072 + i] = f2bf(wk[si]);
        wb[262144 + i] = f2bf(wv[si]);
    } else {
        int r = bid - 512;
        int n0 = (r & 15) * 64, c0 = ((r >> 4) & 3) * 64, b = r >> 6;
#pragma unroll
        for (int p = 0; p < 4; ++p) {
            int c = p * 16 + (tid >> 4);
            int nn = (tid & 15) * 4;
            float4 v = *(const float4*)&x[((size_t)(b * 256) + c0 + c) * 1024 + n0 + nn];
            Lt[c][nn + 0] = v.x; Lt[c][nn + 1] = v.y;
            Lt[c][nn + 2] = v.z; Lt[c][nn + 3] = v.w;
        }
        __syncthreads();
#pragma unroll
        for (int p = 0; p < 4; ++p) {
            int n = p * 16 + (tid >> 4);
            int cc = (tid & 15) * 4;
            ushort4 st;
            st.x = f2bf(Lt[cc + 0][n]); st.y = f2bf(Lt[cc + 1][n]);
            st.z = f2bf(Lt[cc + 2][n]); st.w = f2bf(Lt[cc + 3][n]);
            *(ushort4*)&xT[((size_t)(b << 10) + n0 + n) * 256 + c0 + cc] = st;
        }
    }
}

// ---------------------------------------------------------------------------
// Fused QKV GEMM (round 25): 256x128 tile, 512 thr / 8 waves, parity pipeline
// K-step 32. Grid (8 nt, 6 mt2, 16 b) = 768 blocks, LDS 48KB -> 3 blocks/CU
// = 24 waves/CU. mat = mt2>>1; within-mat row base (mt2&1)*256.
// mat 0=Q token-major [bh][n][64]; mat 1=K (pre-scaled 0.125*log2e) token-
// major; mat 2=V d-major [bh][64][n].
// ---------------------------------------------------------------------------
__global__ __launch_bounds__(512) void qkv_mfma(
    const u16* __restrict__ xT, const u16* __restrict__ wb,
    const float* __restrict__ wq, const float* __restrict__ wk,
    const float* __restrict__ wv,
    const float* __restrict__ bq, const float* __restrict__ bk,
    const float* __restrict__ bv,
    u16* __restrict__ qkvbuf)
{
    __shared__ u16 Wl[256 * 64];   // logical (row, lc): phys = row*64 + (lc ^ ((row&7)<<3))
    __shared__ u16 Tl[128 * 64];   // lc in [0,32) = parity 0, [32,64) = parity 1
    const int tid = threadIdx.x;
    const int lane = tid & 63, w = tid >> 6;          // w in [0,8)
    const int quad = lane >> 4, m15 = lane & 15;
    const int n0 = blockIdx.x * 128, mt2 = blockIdx.y, b = blockIdx.z;
    const int mat = mt2 >> 1;
    const int m0 = mt2 * 256;                   // row in combined W [0,1536)
    const float* worig = (mat == 0) ? wq : ((mat == 1) ? wk : wv);
    const float* bias  = (mat == 0) ? bq : ((mat == 1) ? bk : bv);
    const float oscale = (mat == 1) ? 0.1803368801111204f : 1.0f;  // 0.125*log2(e)
    u16* outbuf = qkvbuf + (size_t)mat * 8388608;

    float4_ acc[2][8];
#pragma unroll
    for (int s = 0; s < 2; ++s)
#pragma unroll
        for (int t = 0; t < 8; ++t) acc[s][t] = (float4_){0, 0, 0, 0};

    // staging: thread covers W rows {srw, srw+128} and T row srw; 8 cols at sc8
    const int srw = tid >> 2;                  // 0..127
    const int sc8 = (tid & 3) * 8;             // 0,8,16,24 (within 32-col K-step)
    const int rdsw = (m15 & 7) << 3;           // fragment-read col XOR
    const int sw0  = (srw & 7) << 3;           // staging swizzle (rows srw, srw+128 share &7)

    const u16* wsrc  = wb + (size_t)(m0 + srw) * 256 + sc8;
    const u16* wsrc2 = wsrc + (size_t)128 * 256;
    const u16* tsrc  = xT + ((size_t)(b << 10) + n0 + srw) * 256 + sc8;

    // prologue: stage K-step 0 into parity 0
    {
        short8 w0 = *(const short8*)(wsrc);
        short8 w1 = *(const short8*)(wsrc2);
        short8 t0 = *(const short8*)(tsrc);
        *(short8*)&Wl[srw * 64 + (sc8 ^ sw0)]         = w0;
        *(short8*)&Wl[(srw + 128) * 64 + (sc8 ^ sw0)] = w1;
        *(short8*)&Tl[srw * 64 + (sc8 ^ sw0)]         = t0;
    }
    __syncthreads();

#pragma unroll
    for (int k = 0; k < 8; ++k) {
        const int p = k & 1;
        short8 pw0, pw1, pt0;
        if (k < 7) {                           // issue next-step loads (regs)
            const int kc = (k + 1) * 32;
            pw0 = *(const short8*)(wsrc + kc);
            pw1 = *(const short8*)(wsrc2 + kc);
            pt0 = *(const short8*)(tsrc + kc);
        }

        // compute step k on parity p (logical col base p*32 + quad*8)
        const int cb = p * 32 + quad * 8;
        short8 af0 = *(const short8*)&Wl[(w * 32 + m15) * 64 + (cb ^ rdsw)];
        short8 af1 = *(const short8*)&Wl[(w * 32 + 16 + m15) * 64 + (cb ^ rdsw)];
        __builtin_amdgcn_s_setprio(1);
#pragma unroll
        for (int t = 0; t < 8; ++t) {
            short8 bf = *(const short8*)&Tl[(t * 16 + m15) * 64 + (cb ^ rdsw)];
            acc[0][t] = MFMA16(af0, bf, acc[0][t]);
            acc[1][t] = MFMA16(af1, bf, acc[1][t]);
        }
        __builtin_amdgcn_s_setprio(0);

        if (k < 7) {                           // write parity p^1 (vmcnt wait here;
            const int pc = (p ^ 1) * 32 + sc8; //  other waves only read parity p)
            *(short8*)&Wl[srw * 64 + (pc ^ sw0)]         = pw0;
            *(short8*)&Wl[(srw + 128) * 64 + (pc ^ sw0)] = pw1;
            *(short8*)&Tl[srw * 64 + (pc ^ sw0)]         = pt0;
        }
        __syncthreads();
    }

    // epilogue: rank-2 pos + bias, scale, store. om = row within this mat's 512.
#pragma unroll
    for (int s = 0; s < 2; ++s) {
        const int om_base = (mt2 & 1) * 256 + w * 32 + s * 16;   // [0,512)
        float wg[4], wx[4], bi[4];
#pragma unroll
        for (int r = 0; r < 4; ++r) {
            int om = om_base + quad * 4 + r;
            wg[r] = worig[(size_t)om * 258 + 256];
            wx[r] = worig[(size_t)om * 258 + 257];
            bi[r] = bias[om];
        }
        const int h = om_base >> 6;
        const int dbase = (om_base & 63) + quad * 4;
#pragma unroll
        for (int t = 0; t < 8; ++t) {
            int n = n0 + t * 16 + m15;
            float gy = -1.0f + 2.0f * (float)(n >> 5) / 31.0f;
            float gx = -1.0f + 2.0f * (float)(n & 31) / 31.0f;
            float v[4];
#pragma unroll
            for (int r = 0; r < 4; ++r)
                v[r] = (acc[s][t][r] + wg[r] * gy + wx[r] * gx + bi[r]) * oscale;
            if (mat != 2) {      // token-major [bh][n][64]
                ushort4 st;
                st.x = f2bf(v[0]); st.y = f2bf(v[1]);
                st.z = f2bf(v[2]); st.w = f2bf(v[3]);
                *(ushort4*)&outbuf[((size_t)(b * 8 + h) * 1024 + n) * 64 + dbase] = st;
            } else {             // d-major [bh][64][n]
#pragma unroll
                for (int r = 0; r < 4; ++r)
                    outbuf[((size_t)(b * 8 + h) * 64 + dbase + r) * 1024 + n] = f2bf(v[r]);
            }
        }
    }
}

// ---------------------------------------------------------------------------
// Attention (round 21, best measured 47.9us): block = (bh, q-tile 256),
// 8 waves x 32 q-rows (2 subs), 512 threads. Swapped QK^T; exp2 softmax; P
// redistributed to GEMM2 B-frags IN-REGISTER via permlane16/32_swap (no Pl
// LDS, 0 conflicts). Output in-place over qbuf [bh][n][64].
// Grid (128 bh, 4 qt). LDS 16.4KB.
// ---------------------------------------------------------------------------
__global__ __launch_bounds__(512) void attn_mfma(
    u16* __restrict__ qbuf, const u16* __restrict__ kbuf,
    const u16* __restrict__ vbuf)
{
    __shared__ u16 Kl[64 * 64];        // [kt][d], elem(kt,d) at kt*64 + (d ^ ((kt&7)<<3))
    __shared__ u16 Vl[64 * 64];        // V^T [d][kt], elem(d,kt) at d*64 + (kt ^ ((d&7)<<3))

    const int tid = threadIdx.x;
    const int lane = tid & 63, w = tid >> 6;          // w in [0,8)
    const int quad = lane >> 4, m15 = lane & 15;
    const int bh = blockIdx.x;
    const int q0 = blockIdx.y * 256;
    u16* qb = qbuf + (size_t)bh * 65536;
    const u16* kb = kbuf + (size_t)bh * 65536;   // [1024 n][64 d]
    const u16* vb = vbuf + (size_t)bh * 65536;   // [64 d][1024 n]

    // Q frags (B-operand): wave w owns q rows q0 + w*32 + s*16 + [0,16)
    short8 qf[2][2];
#pragma unroll
    for (int s = 0; s < 2; ++s) {
        const u16* qr = qb + (size_t)(q0 + w * 32 + s * 16 + m15) * 64 + quad * 8;
        qf[s][0] = *(const short8*)qr;
        qf[s][1] = *(const short8*)(qr + 32);
    }

    float4_ O[2][4];                 // O^T tiles per sub
    float lp[2] = {0.0f, 0.0f};      // per-lane partial l (one scalar per sub)
#pragma unroll
    for (int s = 0; s < 2; ++s)
#pragma unroll
        for (int t = 0; t < 4; ++t) O[s][t] = (float4_){0, 0, 0, 0};

    const int row = tid >> 3, c8 = (tid & 7) * 8;     // 512 thr cover 64 rows x 64 cols
    const int stsw = c8 ^ ((row & 7) << 3);           // K/V staging col swizzle (u16)
    const int rdsw = (m15 & 7) << 3;                  // K/V fragment-read col XOR (u16)

    for (int kt0 = 0; kt0 < 1024; kt0 += 64) {
        __syncthreads();
        *(short8*)&Kl[row * 64 + stsw] =
            *(const short8*)(kb + (size_t)(kt0 + row) * 64 + c8);
        *(short8*)&Vl[row * 64 + stsw] =
            *(const short8*)(vb + (size_t)row * 1024 + kt0 + c8);
        __syncthreads();

        // GEMM1 (swapped): lane holds S^T[kt=t*16+quad*4+r][q'=m15], per sub
        float4_ S[2][4];
#pragma unroll
        for (int s = 0; s < 2; ++s)
#pragma unroll
            for (int t = 0; t < 4; ++t) S[s][t] = (float4_){0, 0, 0, 0};
#pragma unroll
        for (int c = 0; c < 2; ++c) {
            short8 kf[4];
#pragma unroll
            for (int t = 0; t < 4; ++t)
                kf[t] = *(const short8*)&Kl[(t * 16 + m15) * 64 +
                                            ((c * 32 + quad * 8) ^ rdsw)];
            __builtin_amdgcn_s_setprio(1);
#pragma unroll
            for (int s = 0; s < 2; ++s)
#pragma unroll
                for (int t = 0; t < 4; ++t)
                    S[s][t] = MFMA16(kf[t], qf[s][c], S[s][t]);
            __builtin_amdgcn_s_setprio(0);
        }

        // exp2 + pack: W0[s][t] = {p[t][0],p[t][1]}, W1[s][t] = {p[t][2],p[t][3]}
        u32 W0[2][4], W1[2][4];
#pragma unroll
        for (int s = 0; s < 2; ++s) {
            float lsum = 0.0f;
#pragma unroll
            for (int t = 0; t < 4; ++t) {
                float p0 = exp2_fast(S[s][t][0]);
                float p1 = exp2_fast(S[s][t][1]);
                float p2 = exp2_fast(S[s][t][2]);
                float p3 = exp2_fast(S[s][t][3]);
                W0[s][t] = cvtpk_bf16(p0, p1);
                W1[s][t] = cvtpk_bf16(p2, p3);
                lsum += (p0 + p1) + (p2 + p3);
            }
            lp[s] += lsum;
        }

        // GEMM2: O^T[d][q'] += V^T[d][kt] * P^T[kt][q']. B-frag built in-reg:
        // u0,u2 = p16(p32(W0[2c], W0[2c+1])), u1,u3 = p16(p32(W1[2c], W1[2c+1])).
#pragma unroll
        for (int c = 0; c < 2; ++c) {
            short8 av[4];
#pragma unroll
            for (int dt = 0; dt < 4; ++dt)
                av[dt] = *(const short8*)&Vl[(dt * 16 + m15) * 64 +
                                             ((c * 32 + quad * 8) ^ rdsw)];
#pragma unroll
            for (int s = 0; s < 2; ++s) {
                u32 a = W0[s][2 * c], d = W0[s][2 * c + 1];
                pl32swap(a, d); pl16swap(a, d);        // a=u0, d=u2
                u32 bb = W1[s][2 * c], e = W1[s][2 * c + 1];
                pl32swap(bb, e); pl16swap(bb, e);      // bb=u1, e=u3
                union { u32 u[4]; short8 v; } bpu;
                bpu.u[0] = a; bpu.u[1] = bb; bpu.u[2] = d; bpu.u[3] = e;
                short8 bp = bpu.v;
                __builtin_amdgcn_s_setprio(1);
#pragma unroll
                for (int dt = 0; dt < 4; ++dt)
                    O[s][dt] = MFMA16(av[dt], bp, O[s][dt]);
                __builtin_amdgcn_s_setprio(0);
            }
        }
    }

    // l: sum the 4 quad partials for column q'=m15 (all lanes end with full l)
#pragma unroll
    for (int s = 0; s < 2; ++s) {
        float v = lp[s];
        v += __shfl_xor(v, 16);
        v += __shfl_xor(v, 32);
        float linv = 1.0f / v;
        int n = q0 + w * 32 + s * 16 + m15;
#pragma unroll
        for (int dt = 0; dt < 4; ++dt) {
            ushort4 st;
            st.x = f2bf(O[s][dt][0] * linv);
            st.y = f2bf(O[s][dt][1] * linv);
            st.z = f2bf(O[s][dt][2] * linv);
            st.w = f2bf(O[s][dt][3] * linv);
            // in-place over qbuf: [bh][n][64]
            *(ushort4*)&qb[(size_t)n * 64 + dt * 16 + quad * 4] = st;
        }
    }
}

// ---------------------------------------------------------------------------
// Output projection + bias + residual (parity pipeline, round 24).
// AO read from qbuf [bh][n][64]. Grid (16 nt, 4 ft, 16 b). K-step 32 over
// [64][64] double-parity swizzled LDS; 16 steps x 1 barrier; next step's
// W (8 fp32) + T (short8) loads issued one step ahead; cvt_pk at write point.
// ---------------------------------------------------------------------------
__global__ __launch_bounds__(256) void proj_mfma(
    const u16* __restrict__ ao, const float* __restrict__ wo,
    const float* __restrict__ bo, const float* __restrict__ x,
    float* __restrict__ out)
{
    __shared__ u16 Wl[64 * 64];    // logical (row, lc): phys = row*64 + (lc ^ ((row&7)<<3))
    __shared__ u16 Tl[64 * 64];    // lc in [0,32) = parity 0, [32,64) = parity 1
    const int tid = threadIdx.x;
    const int lane = tid & 63, w = tid >> 6;
    const int quad = lane >> 4, m15 = lane & 15;
    const int n0 = blockIdx.x * 64, f0 = blockIdx.y * 64, b = blockIdx.z;

    float4_ acc[4] = {{0,0,0,0},{0,0,0,0},{0,0,0,0},{0,0,0,0}};
    const int srow = tid >> 2;                 // 0..63
    const int sc8  = (tid & 3) * 8;            // 0,8,16,24 (within 32-col K-step)
    const int sw0  = (srow & 7) << 3;
    const int rdsw = (m15 & 7) << 3;

    const float* wsrc = wo + (size_t)(f0 + srow) * 512 + sc8;   // + kc
    const u16* tbase = ao + ((size_t)(b << 3) * 1024 + n0 + srow) * 64 + sc8;

    // prologue: stage step 0 into parity 0
    {
        float4 v0 = *(const float4*)(wsrc);
        float4 v1 = *(const float4*)(wsrc + 4);
        uint4 pk;
        pk.x = cvtpk_bf16(v0.x, v0.y); pk.y = cvtpk_bf16(v0.z, v0.w);
        pk.z = cvtpk_bf16(v1.x, v1.y); pk.w = cvtpk_bf16(v1.z, v1.w);
        *(uint4*)&Wl[srow * 64 + (sc8 ^ sw0)] = pk;
        *(short8*)&Tl[srow * 64 + (sc8 ^ sw0)] = *(const short8*)(tbase);
    }
    __syncthreads();

#pragma unroll
    for (int k = 0; k < 16; ++k) {
        const int p = k & 1;
        float4 pv0, pv1; short8 pt;
        if (k < 15) {                          // issue next-step loads (regs)
            const int kc = (k + 1) * 32;
            pv0 = *(const float4*)(wsrc + kc);
            pv1 = *(const float4*)(wsrc + kc + 4);
            pt  = *(const short8*)(tbase + (size_t)(kc >> 6) * 65536 + (kc & 63));
        }

        // compute step k on parity p
        const int cb = p * 32 + quad * 8;
        short8 af = *(const short8*)&Wl[(w * 16 + m15) * 64 + (cb ^ rdsw)];
        __builtin_amdgcn_s_setprio(1);
#pragma unroll
        for (int t = 0; t < 4; ++t) {
            short8 bf = *(const short8*)&Tl[(t * 16 + m15) * 64 + (cb ^ rdsw)];
            acc[t] = MFMA16(af, bf, acc[t]);
        }
        __builtin_amdgcn_s_setprio(0);

        if (k < 15) {                          // write parity p^1 (vmcnt wait here)
            const int pc = ((p ^ 1) * 32 + sc8) ^ sw0;
            uint4 pk;
            pk.x = cvtpk_bf16(pv0.x, pv0.y); pk.y = cvtpk_bf16(pv0.z, pv0.w);
            pk.z = cvtpk_bf16(pv1.x, pv1.y); pk.w = cvtpk_bf16(pv1.z, pv1.w);
            *(uint4*)&Wl[srow * 64 + pc] = pk;
            *(short8*)&Tl[srow * 64 + pc] = pt;
        }
        __syncthreads();
    }

    float bi[4];
#pragma unroll
    for (int r = 0; r < 4; ++r) bi[r] = bo[f0 + w * 16 + quad * 4 + r];
#pragma unroll
    for (int t = 0; t < 4; ++t) {
        int n = n0 + t * 16 + m15;
#pragma unroll
        for (int r = 0; r < 4; ++r) {
            int f = f0 + w * 16 + quad * 4 + r;
            size_t idx = ((size_t)(b * 256) + f) * 1024 + n;
            out[idx] = acc[t][r] + bi[r] + x[idx];
        }
    }
}

extern "C" void kernel_launch(void* const* d_in, const int* in_sizes, int n_in,
                              void* d_out, int out_size, void* d_ws, size_t ws_size,
                              hipStream_t stream) {
    const float* x  = (const float*)d_in[0];
    const float* wq = (const float*)d_in[1];
    const float* bq = (const float*)d_in[2];
    const float* wk = (const float*)d_in[3];
    const float* bk = (const float*)d_in[4];
    const float* wv = (const float*)d_in[5];
    const float* bv = (const float*)d_in[6];
    const float* wo = (const float*)d_in[7];
    const float* bo = (const float*)d_in[8];

    // ws layout (u16 elems), ~59.8 MiB used:
    //   qkvbuf: 3 x 8,388,608 (Q, K, V). attn writes AO in-place over Q.
    //   region: xT[4,194,304] + wb[393,216] — no aliasing with anything live.
    u16* qkvbuf = (u16*)d_ws;
    u16* region = qkvbuf + 3 * 8388608;
    u16* xT = region;
    u16* wb = region + 4194304;

    prep<<<1536, 256, 0, stream>>>(wq, wk, wv, x, wb, xT);

    qkv_mfma<<<dim3(8, 6, 16), 512, 0, stream>>>(
        xT, wb, wq, wk, wv, bq, bk, bv, qkvbuf);

    attn_mfma<<<dim3(128, 4), 512, 0, stream>>>(
        qkvbuf, qkvbuf + 8388608, qkvbuf + 16777216);

    proj_mfma<<<dim3(16, 4, 16), 256, 0, stream>>>(qkvbuf, wo, bo, x, (float*)d_out);
}

// Round 19
// 163.289 us; speedup vs baseline: 1.0275x; 1.0275x over previous
//
#include <hip/hip_runtime.h>

// ResidualAttentionBlock (MFMA, round 26): B=16, FIN=256, H=W=32 (N=1024),
// NH=8, FH=64, CIN=258, COUT=512. Inputs fp32. v_mfma_f32_16x16x32_bf16,
// fp32 accumulation.
//
// Round 26 (qkv only; attn = r21 best 48.3us, proj = r24, prep unchanged):
//  - qkv measured (r25): 48.2us, MfmaUtil 9.5% -> vmcnt stall at mid-step
//    ds_write of prefetched regs (only ~200cy of MFMA covers a ~400cy load).
//  - qkv staging -> global_load_lds DMA into PARITY-MAJOR LDS
//    (Wl2[2][256][32] + Tl2[2][128][32] = 48KB, same 3 blocks/CU):
//    3 DMA instr/wave/step (2 W chunks + 1 T chunk, 16 rows x 64B each)
//    issued at step top into parity p^1; the end-of-step barrier drains them
//    after a FULL step of compute (attn-r22 pattern). ds_writes deleted,
//    zero VGPR cost.
//  - Both-sides swizzle: global source 16B-slot = li2 ^ ((row>>1)&3);
//    fragment read slot = quad ^ ((row>>1)&3) -> collapses to constant
//    sfr = (quad ^ ((m15>>1)&3))*8 (w*16, t*8 both = 0 mod 4). Read banks:
//    (m15&1)*16 + (quad^((m15>>1)&3))*4 -> 8 distinct per 8 rows, 2-way free.

typedef unsigned short u16;
typedef unsigned int   u32;
typedef __attribute__((ext_vector_type(8))) short  short8;
typedef __attribute__((ext_vector_type(4))) float  float4_;

#define MFMA16(a, b, c) __builtin_amdgcn_mfma_f32_16x16x32_bf16(a, b, c, 0, 0, 0)
#define GLOAD_LDS16(g, l) \
    __builtin_amdgcn_global_load_lds((const __attribute__((address_space(1))) void*)(g), \
                                     (__attribute__((address_space(3))) void*)(l), 16, 0, 0)

__device__ __forceinline__ float bf2f(u16 u) {
    union { u32 i; float f; } v; v.i = ((u32)u) << 16; return v.f;
}
__device__ __forceinline__ u16 f2bf(float f) {           // RNE
    union { float f; u32 i; } v; v.f = f;
    u32 r = v.i + 0x7FFFu + ((v.i >> 16) & 1u);
    return (u16)(r >> 16);
}
__device__ __forceinline__ float exp2_fast(float x) {    // 2^x
    float r;
    asm("v_exp_f32 %0, %1" : "=v"(r) : "v"(x));
    return r;
}
__device__ __forceinline__ u32 cvtpk_bf16(float lo, float hi) {  // {bf16(lo), bf16(hi)}
    u32 r;
    asm("v_cvt_pk_bf16_f32 %0, %1, %2" : "=v"(r) : "v"(lo), "v"(hi));
    return r;
}
// rows = 16-lane groups r0..r3. p32: x'=[x0,x1,y0,y1], y'=[x2,x3,y2,y3]
__device__ __forceinline__ void pl32swap(u32 &x, u32 &y) {
    asm volatile("v_permlane32_swap_b32 %0, %1" : "+v"(x), "+v"(y));
}
// p16: x'=[x0,y0,x2,y2], y'=[x1,y1,x3,y3]
__device__ __forceinline__ void pl16swap(u32 &x, u32 &y) {
    asm volatile("v_permlane16_swap_b32 %0, %1" : "+v"(x), "+v"(y));
}

// ---------------------------------------------------------------------------
// prep: blocks [0,512) convert wq/wk/wv [512][258] fp32 -> wb [1536][256] bf16
//       blocks [512,1536) transpose x [b][256][1024] fp32 -> xT [b][1024][256]
// ---------------------------------------------------------------------------
__global__ __launch_bounds__(256) void prep(
    const float* __restrict__ wq, const float* __restrict__ wk,
    const float* __restrict__ wv, const float* __restrict__ x,
    u16* __restrict__ wb, u16* __restrict__ xT)
{
    __shared__ float Lt[64][65];
    const int bid = blockIdx.x;
    const int tid = threadIdx.x;
    if (bid < 512) {
        int i = bid * 256 + tid;
        int o = i >> 8, c = i & 255;
        size_t si = (size_t)o * 258 + c;
        wb[i]          = f2bf(wq[si]);
        wb[131072 + i] = f2bf(wk[si]);
        wb[262144 + i] = f2bf(wv[si]);
    } else {
        int r = bid - 512;
        int n0 = (r & 15) * 64, c0 = ((r >> 4) & 3) * 64, b = r >> 6;
#pragma unroll
        for (int p = 0; p < 4; ++p) {
            int c = p * 16 + (tid >> 4);
            int nn = (tid & 15) * 4;
            float4 v = *(const float4*)&x[((size_t)(b * 256) + c0 + c) * 1024 + n0 + nn];
            Lt[c][nn + 0] = v.x; Lt[c][nn + 1] = v.y;
            Lt[c][nn + 2] = v.z; Lt[c][nn + 3] = v.w;
        }
        __syncthreads();
#pragma unroll
        for (int p = 0; p < 4; ++p) {
            int n = p * 16 + (tid >> 4);
            int cc = (tid & 15) * 4;
            ushort4 st;
            st.x = f2bf(Lt[cc + 0][n]); st.y = f2bf(Lt[cc + 1][n]);
            st.z = f2bf(Lt[cc + 2][n]); st.w = f2bf(Lt[cc + 3][n]);
            *(ushort4*)&xT[((size_t)(b << 10) + n0 + n) * 256 + c0 + cc] = st;
        }
    }
}

// ---------------------------------------------------------------------------
// Fused QKV GEMM (round 26): 256x128 tile, 512 thr / 8 waves, DMA parity
// pipeline K-step 32. Grid (8 nt, 6 mt2, 16 b), LDS 48KB parity-major.
// mat = mt2>>1; within-mat row base (mt2&1)*256. mat 0=Q token-major
// [bh][n][64]; mat 1=K (pre-scaled 0.125*log2e) token-major; mat 2=V d-major.
// ---------------------------------------------------------------------------
__global__ __launch_bounds__(512) void qkv_mfma(
    const u16* __restrict__ xT, const u16* __restrict__ wb,
    const float* __restrict__ wq, const float* __restrict__ wk,
    const float* __restrict__ wv,
    const float* __restrict__ bq, const float* __restrict__ bk,
    const float* __restrict__ bv,
    u16* __restrict__ qkvbuf)
{
    __shared__ __align__(1024) u16 Wl2[2][256 * 32];  // [parity][row*32 + physcol]
    __shared__ __align__(1024) u16 Tl2[2][128 * 32];
    const int tid = threadIdx.x;
    const int lane = tid & 63, w = tid >> 6;          // w in [0,8)
    const int quad = lane >> 4, m15 = lane & 15;
    const int n0 = blockIdx.x * 128, mt2 = blockIdx.y, b = blockIdx.z;
    const int mat = mt2 >> 1;
    const int m0 = mt2 * 256;                   // row in combined W [0,1536)
    const float* worig = (mat == 0) ? wq : ((mat == 1) ? wk : wv);
    const float* bias  = (mat == 0) ? bq : ((mat == 1) ? bk : bv);
    const float oscale = (mat == 1) ? 0.1803368801111204f : 1.0f;  // 0.125*log2(e)
    u16* outbuf = qkvbuf + (size_t)mat * 8388608;

    float4_ acc[2][8];
#pragma unroll
    for (int s = 0; s < 2; ++s)
#pragma unroll
        for (int t = 0; t < 8; ++t) acc[s][t] = (float4_){0, 0, 0, 0};

    // DMA lane mapping: 16 rows/chunk, 4 lanes/row (16B each).
    const int lr2 = lane >> 2, li2 = lane & 3;
    const int wrow0 = (2 * w) * 16 + lr2;        // W chunk 2w
    const int wrow1 = (2 * w + 1) * 16 + lr2;    // W chunk 2w+1
    const int trow  = w * 16 + lr2;              // T chunk w
    // pre-swizzled global source: logical 16B-slot = li2 ^ ((row>>1)&3)
    const int wc0 = (li2 ^ ((wrow0 >> 1) & 3)) * 8;
    const int wc1 = (li2 ^ ((wrow1 >> 1) & 3)) * 8;
    const int tc  = (li2 ^ ((trow  >> 1) & 3)) * 8;
    const u16* wsrc0 = wb + (size_t)(m0 + wrow0) * 256 + wc0;
    const u16* wsrc1 = wb + (size_t)(m0 + wrow1) * 256 + wc1;
    const u16* tsrc  = xT + ((size_t)(b << 10) + n0 + trow) * 256 + tc;

    // fragment-read slot (constant: w*16 and t*8 are 0 mod 4)
    const int sfr = (quad ^ ((m15 >> 1) & 3)) * 8;
    const int ra0 = (w * 32 + m15) * 32 + sfr;
    const int ra1 = (w * 32 + 16 + m15) * 32 + sfr;

    // prologue: DMA K-step 0 into parity 0
    GLOAD_LDS16(wsrc0, &Wl2[0][(2 * w) * 512]);
    GLOAD_LDS16(wsrc1, &Wl2[0][(2 * w + 1) * 512]);
    GLOAD_LDS16(tsrc,  &Tl2[0][w * 512]);
    __syncthreads();

#pragma unroll
    for (int k = 0; k < 8; ++k) {
        const int p = k & 1;
        if (k < 7) {                           // DMA next step into parity p^1
            const int kc = (k + 1) * 32;
            GLOAD_LDS16(wsrc0 + kc, &Wl2[p ^ 1][(2 * w) * 512]);
            GLOAD_LDS16(wsrc1 + kc, &Wl2[p ^ 1][(2 * w + 1) * 512]);
            GLOAD_LDS16(tsrc + kc,  &Tl2[p ^ 1][w * 512]);
        }

        short8 af0 = *(const short8*)&Wl2[p][ra0];
        short8 af1 = *(const short8*)&Wl2[p][ra1];
        __builtin_amdgcn_s_setprio(1);
#pragma unroll
        for (int t = 0; t < 8; ++t) {
            short8 bf = *(const short8*)&Tl2[p][(t * 16 + m15) * 32 + sfr];
            acc[0][t] = MFMA16(af0, bf, acc[0][t]);
            acc[1][t] = MFMA16(af1, bf, acc[1][t]);
        }
        __builtin_amdgcn_s_setprio(0);

        // barrier drains this step's DMA (issued at step top, covered by the
        // full compute above) and publishes parity p^1 for step k+1.
        __syncthreads();
    }

    // epilogue: rank-2 pos + bias, scale, store. om = row within this mat's 512.
#pragma unroll
    for (int s = 0; s < 2; ++s) {
        const int om_base = (mt2 & 1) * 256 + w * 32 + s * 16;   // [0,512)
        float wg[4], wx[4], bi[4];
#pragma unroll
        for (int r = 0; r < 4; ++r) {
            int om = om_base + quad * 4 + r;
            wg[r] = worig[(size_t)om * 258 + 256];
            wx[r] = worig[(size_t)om * 258 + 257];
            bi[r] = bias[om];
        }
        const int h = om_base >> 6;
        const int dbase = (om_base & 63) + quad * 4;
#pragma unroll
        for (int t = 0; t < 8; ++t) {
            int n = n0 + t * 16 + m15;
            float gy = -1.0f + 2.0f * (float)(n >> 5) / 31.0f;
            float gx = -1.0f + 2.0f * (float)(n & 31) / 31.0f;
            float v[4];
#pragma unroll
            for (int r = 0; r < 4; ++r)
                v[r] = (acc[s][t][r] + wg[r] * gy + wx[r] * gx + bi[r]) * oscale;
            if (mat != 2) {      // token-major [bh][n][64]
                ushort4 st;
                st.x = f2bf(v[0]); st.y = f2bf(v[1]);
                st.z = f2bf(v[2]); st.w = f2bf(v[3]);
                *(ushort4*)&outbuf[((size_t)(b * 8 + h) * 1024 + n) * 64 + dbase] = st;
            } else {             // d-major [bh][64][n]
#pragma unroll
                for (int r = 0; r < 4; ++r)
                    outbuf[((size_t)(b * 8 + h) * 64 + dbase + r) * 1024 + n] = f2bf(v[r]);
            }
        }
    }
}

// ---------------------------------------------------------------------------
// Attention (round 21, best measured 47.9-48.3us): block = (bh, q-tile 256),
// 8 waves x 32 q-rows (2 subs), 512 threads. Swapped QK^T; exp2 softmax; P
// redistributed to GEMM2 B-frags IN-REGISTER via permlane16/32_swap (no Pl
// LDS, 0 conflicts). Output in-place over qbuf [bh][n][64].
// Grid (128 bh, 4 qt). LDS 16.4KB.
// ---------------------------------------------------------------------------
__global__ __launch_bounds__(512) void attn_mfma(
    u16* __restrict__ qbuf, const u16* __restrict__ kbuf,
    const u16* __restrict__ vbuf)
{
    __shared__ u16 Kl[64 * 64];        // [kt][d], elem(kt,d) at kt*64 + (d ^ ((kt&7)<<3))
    __shared__ u16 Vl[64 * 64];        // V^T [d][kt], elem(d,kt) at d*64 + (kt ^ ((d&7)<<3))

    const int tid = threadIdx.x;
    const int lane = tid & 63, w = tid >> 6;          // w in [0,8)
    const int quad = lane >> 4, m15 = lane & 15;
    const int bh = blockIdx.x;
    const int q0 = blockIdx.y * 256;
    u16* qb = qbuf + (size_t)bh * 65536;
    const u16* kb = kbuf + (size_t)bh * 65536;   // [1024 n][64 d]
    const u16* vb = vbuf + (size_t)bh * 65536;   // [64 d][1024 n]

    // Q frags (B-operand): wave w owns q rows q0 + w*32 + s*16 + [0,16)
    short8 qf[2][2];
#pragma unroll
    for (int s = 0; s < 2; ++s) {
        const u16* qr = qb + (size_t)(q0 + w * 32 + s * 16 + m15) * 64 + quad * 8;
        qf[s][0] = *(const short8*)qr;
        qf[s][1] = *(const short8*)(qr + 32);
    }

    float4_ O[2][4];                 // O^T tiles per sub
    float lp[2] = {0.0f, 0.0f};      // per-lane partial l (one scalar per sub)
#pragma unroll
    for (int s = 0; s < 2; ++s)
#pragma unroll
        for (int t = 0; t < 4; ++t) O[s][t] = (float4_){0, 0, 0, 0};

    const int row = tid >> 3, c8 = (tid & 7) * 8;     // 512 thr cover 64 rows x 64 cols
    const int stsw = c8 ^ ((row & 7) << 3);           // K/V staging col swizzle (u16)
    const int rdsw = (m15 & 7) << 3;                  // K/V fragment-read col XOR (u16)

    for (int kt0 = 0; kt0 < 1024; kt0 += 64) {
        __syncthreads();
        *(short8*)&Kl[row * 64 + stsw] =
            *(const short8*)(kb + (size_t)(kt0 + row) * 64 + c8);
        *(short8*)&Vl[row * 64 + stsw] =
            *(const short8*)(vb + (size_t)row * 1024 + kt0 + c8);
        __syncthreads();

        // GEMM1 (swapped): lane holds S^T[kt=t*16+quad*4+r][q'=m15], per sub
        float4_ S[2][4];
#pragma unroll
        for (int s = 0; s < 2; ++s)
#pragma unroll
            for (int t = 0; t < 4; ++t) S[s][t] = (float4_){0, 0, 0, 0};
#pragma unroll
        for (int c = 0; c < 2; ++c) {
            short8 kf[4];
#pragma unroll
            for (int t = 0; t < 4; ++t)
                kf[t] = *(const short8*)&Kl[(t * 16 + m15) * 64 +
                                            ((c * 32 + quad * 8) ^ rdsw)];
            __builtin_amdgcn_s_setprio(1);
#pragma unroll
            for (int s = 0; s < 2; ++s)
#pragma unroll
                for (int t = 0; t < 4; ++t)
                    S[s][t] = MFMA16(kf[t], qf[s][c], S[s][t]);
            __builtin_amdgcn_s_setprio(0);
        }

        // exp2 + pack: W0[s][t] = {p[t][0],p[t][1]}, W1[s][t] = {p[t][2],p[t][3]}
        u32 W0[2][4], W1[2][4];
#pragma unroll
        for (int s = 0; s < 2; ++s) {
            float lsum = 0.0f;
#pragma unroll
            for (int t = 0; t < 4; ++t) {
                float p0 = exp2_fast(S[s][t][0]);
                float p1 = exp2_fast(S[s][t][1]);
                float p2 = exp2_fast(S[s][t][2]);
                float p3 = exp2_fast(S[s][t][3]);
                W0[s][t] = cvtpk_bf16(p0, p1);
                W1[s][t] = cvtpk_bf16(p2, p3);
                lsum += (p0 + p1) + (p2 + p3);
            }
            lp[s] += lsum;
        }

        // GEMM2: O^T[d][q'] += V^T[d][kt] * P^T[kt][q']. B-frag built in-reg:
        // u0,u2 = p16(p32(W0[2c], W0[2c+1])), u1,u3 = p16(p32(W1[2c], W1[2c+1])).
#pragma unroll
        for (int c = 0; c < 2; ++c) {
            short8 av[4];
#pragma unroll
            for (int dt = 0; dt < 4; ++dt)
                av[dt] = *(const short8*)&Vl[(dt * 16 + m15) * 64 +
                                             ((c * 32 + quad * 8) ^ rdsw)];
#pragma unroll
            for (int s = 0; s < 2; ++s) {
                u32 a = W0[s][2 * c], d = W0[s][2 * c + 1];
                pl32swap(a, d); pl16swap(a, d);        // a=u0, d=u2
                u32 bb = W1[s][2 * c], e = W1[s][2 * c + 1];
                pl32swap(bb, e); pl16swap(bb, e);      // bb=u1, e=u3
                union { u32 u[4]; short8 v; } bpu;
                bpu.u[0] = a; bpu.u[1] = bb; bpu.u[2] = d; bpu.u[3] = e;
                short8 bp = bpu.v;
                __builtin_amdgcn_s_setprio(1);
#pragma unroll
                for (int dt = 0; dt < 4; ++dt)
                    O[s][dt] = MFMA16(av[dt], bp, O[s][dt]);
                __builtin_amdgcn_s_setprio(0);
            }
        }
    }

    // l: sum the 4 quad partials for column q'=m15 (all lanes end with full l)
#pragma unroll
    for (int s = 0; s < 2; ++s) {
        float v = lp[s];
        v += __shfl_xor(v, 16);
        v += __shfl_xor(v, 32);
        float linv = 1.0f / v;
        int n = q0 + w * 32 + s * 16 + m15;
#pragma unroll
        for (int dt = 0; dt < 4; ++dt) {
            ushort4 st;
            st.x = f2bf(O[s][dt][0] * linv);
            st.y = f2bf(O[s][dt][1] * linv);
            st.z = f2bf(O[s][dt][2] * linv);
            st.w = f2bf(O[s][dt][3] * linv);
            // in-place over qbuf: [bh][n][64]
            *(ushort4*)&qb[(size_t)n * 64 + dt * 16 + quad * 4] = st;
        }
    }
}

// ---------------------------------------------------------------------------
// Output projection + bias + residual (parity pipeline, round 24).
// AO read from qbuf [bh][n][64]. Grid (16 nt, 4 ft, 16 b). K-step 32 over
// [64][64] double-parity swizzled LDS; 16 steps x 1 barrier; next step's
// W (8 fp32) + T (short8) loads issued one step ahead; cvt_pk at write point.
// ---------------------------------------------------------------------------
__global__ __launch_bounds__(256) void proj_mfma(
    const u16* __restrict__ ao, const float* __restrict__ wo,
    const float* __restrict__ bo, const float* __restrict__ x,
    float* __restrict__ out)
{
    __shared__ u16 Wl[64 * 64];    // logical (row, lc): phys = row*64 + (lc ^ ((row&7)<<3))
    __shared__ u16 Tl[64 * 64];    // lc in [0,32) = parity 0, [32,64) = parity 1
    const int tid = threadIdx.x;
    const int lane = tid & 63, w = tid >> 6;
    const int quad = lane >> 4, m15 = lane & 15;
    const int n0 = blockIdx.x * 64, f0 = blockIdx.y * 64, b = blockIdx.z;

    float4_ acc[4] = {{0,0,0,0},{0,0,0,0},{0,0,0,0},{0,0,0,0}};
    const int srow = tid >> 2;                 // 0..63
    const int sc8  = (tid & 3) * 8;            // 0,8,16,24 (within 32-col K-step)
    const int sw0  = (srow & 7) << 3;
    const int rdsw = (m15 & 7) << 3;

    const float* wsrc = wo + (size_t)(f0 + srow) * 512 + sc8;   // + kc
    const u16* tbase = ao + ((size_t)(b << 3) * 1024 + n0 + srow) * 64 + sc8;

    // prologue: stage step 0 into parity 0
    {
        float4 v0 = *(const float4*)(wsrc);
        float4 v1 = *(const float4*)(wsrc + 4);
        uint4 pk;
        pk.x = cvtpk_bf16(v0.x, v0.y); pk.y = cvtpk_bf16(v0.z, v0.w);
        pk.z = cvtpk_bf16(v1.x, v1.y); pk.w = cvtpk_bf16(v1.z, v1.w);
        *(uint4*)&Wl[srow * 64 + (sc8 ^ sw0)] = pk;
        *(short8*)&Tl[srow * 64 + (sc8 ^ sw0)] = *(const short8*)(tbase);
    }
    __syncthreads();

#pragma unroll
    for (int k = 0; k < 16; ++k) {
        const int p = k & 1;
        float4 pv0, pv1; short8 pt;
        if (k < 15) {                          // issue next-step loads (regs)
            const int kc = (k + 1) * 32;
            pv0 = *(const float4*)(wsrc + kc);
            pv1 = *(const float4*)(wsrc + kc + 4);
            pt  = *(const short8*)(tbase + (size_t)(kc >> 6) * 65536 + (kc & 63));
        }

        // compute step k on parity p
        const int cb = p * 32 + quad * 8;
        short8 af = *(const short8*)&Wl[(w * 16 + m15) * 64 + (cb ^ rdsw)];
        __builtin_amdgcn_s_setprio(1);
#pragma unroll
        for (int t = 0; t < 4; ++t) {
            short8 bf = *(const short8*)&Tl[(t * 16 + m15) * 64 + (cb ^ rdsw)];
            acc[t] = MFMA16(af, bf, acc[t]);
        }
        __builtin_amdgcn_s_setprio(0);

        if (k < 15) {                          // write parity p^1 (vmcnt wait here)
            const int pc = ((p ^ 1) * 32 + sc8) ^ sw0;
            uint4 pk;
            pk.x = cvtpk_bf16(pv0.x, pv0.y); pk.y = cvtpk_bf16(pv0.z, pv0.w);
            pk.z = cvtpk_bf16(pv1.x, pv1.y); pk.w = cvtpk_bf16(pv1.z, pv1.w);
            *(uint4*)&Wl[srow * 64 + pc] = pk;
            *(short8*)&Tl[srow * 64 + pc] = pt;
        }
        __syncthreads();
    }

    float bi[4];
#pragma unroll
    for (int r = 0; r < 4; ++r) bi[r] = bo[f0 + w * 16 + quad * 4 + r];
#pragma unroll
    for (int t = 0; t < 4; ++t) {
        int n = n0 + t * 16 + m15;
#pragma unroll
        for (int r = 0; r < 4; ++r) {
            int f = f0 + w * 16 + quad * 4 + r;
            size_t idx = ((size_t)(b * 256) + f) * 1024 + n;
            out[idx] = acc[t][r] + bi[r] + x[idx];
        }
    }
}

extern "C" void kernel_launch(void* const* d_in, const int* in_sizes, int n_in,
                              void* d_out, int out_size, void* d_ws, size_t ws_size,
                              hipStream_t stream) {
    const float* x  = (const float*)d_in[0];
    const float* wq = (const float*)d_in[1];
    const float* bq = (const float*)d_in[2];
    const float* wk = (const float*)d_in[3];
    const float* bk = (const float*)d_in[4];
    const float* wv = (const float*)d_in[5];
    const float* bv = (const float*)d_in[6];
    const float* wo = (const float*)d_in[7];
    const float* bo = (const float*)d_in[8];

    // ws layout (u16 elems), ~59.8 MiB used:
    //   qkvbuf: 3 x 8,388,608 (Q, K, V). attn writes AO in-place over Q.
    //   region: xT[4,194,304] + wb[393,216] — no aliasing with anything live.
    u16* qkvbuf = (u16*)d_ws;
    u16* region = qkvbuf + 3 * 8388608;
    u16* xT = region;
    u16* wb = region + 4194304;

    prep<<<1536, 256, 0, stream>>>(wq, wk, wv, x, wb, xT);

    qkv_mfma<<<dim3(8, 6, 16), 512, 0, stream>>>(
        xT, wb, wq, wk, wv, bq, bk, bv, qkvbuf);

    attn_mfma<<<dim3(128, 4), 512, 0, stream>>>(
        qkvbuf, qkvbuf + 8388608, qkvbuf + 16777216);

    proj_mfma<<<dim3(16, 4, 16), 256, 0, stream>>>(qkvbuf, wo, bo, x, (float*)d_out);
}